// Round 18
// baseline (91.664 us; speedup 1.0000x reference)
//
#include <hip/hip_runtime.h>
#include <hip/hip_bf16.h>
#include <cstdint>
#include <cstddef>

// Problem constants
#define BB 64
#define TN 4096
#define FF 128
#define SPLIT 8                  // chunks per batch
#define NBLK (BB * SPLIT)        // 512 blocks x 256 thr, 2 blocks/CU
#define KT 32                    // rows per tile (one K-step)
#define NKT 16                   // phases per block (512 rows)
#define TSTRIDE 72               // bytes per f-row in T

#define NTILE_UP 36
#define TILE_ELEMS 256
#define PART_FLOATS (NTILE_UP * TILE_ELEMS)   // 9216

// ws layout (floats)
#define SUM0_OFF 0
#define MEAN_OFF (SUM0_OFF + BB * FF)
#define RSTD_OFF (MEAN_OFF + BB * FF)
#define SABS_OFF (RSTD_OFF + BB * FF)
#define TRI_OFF  (SABS_OFF + 1)
#define DONE_OFF (TRI_OFF + 1)
#define ZERO_FLOATS (DONE_OFF + 1)
#define R_OFF 24832                           // [BB][9216]
#define P_OFF (R_OFF + BB * PART_FLOATS)      // [NBLK][9216]  (18.9 MB)

typedef __attribute__((ext_vector_type(8))) short bf16x8_t;
typedef __attribute__((ext_vector_type(4))) short short4_t;
typedef __attribute__((ext_vector_type(4))) float f32x4;

// 36 upper-tri tiles split 9 per wave (verified in R8 run)
__device__ __constant__ uint8_t TR[4][9] = {
    {0,0,0,0,0,0,0,0,4},{1,1,1,1,1,1,1,4,4},{2,2,2,2,2,2,4,5,5},{3,3,3,3,3,5,6,6,7}};
__device__ __constant__ uint8_t TC[4][9] = {
    {0,1,2,3,4,5,6,7,4},{1,2,3,4,5,6,7,5,6},{2,3,4,5,6,7,7,5,6},{3,4,5,6,7,7,6,7,7}};
__device__ __constant__ uint8_t TT[4][9] = {
    {0,1,2,3,4,5,6,7,26},{8,9,10,11,12,13,14,27,28},
    {15,16,17,18,19,20,29,30,31},{21,22,23,24,25,32,33,34,35}};

__device__ __constant__ int kRowBaseRT[8] = {0, 8, 15, 21, 26, 30, 33, 35};
__device__ __constant__ int kDiagTr[36] = {
    0,-1,-1,-1,-1,-1,-1,-1, 1,-1,-1,-1,-1,-1,-1, 2,-1,-1,-1,-1,-1,
    3,-1,-1,-1,-1, 4,-1,-1,-1, 5,-1,-1, 6,-1, 7};

static __device__ __forceinline__ unsigned pk2(float lo, float hi) {
    float2 t; t.x = lo; t.y = hi;
    __hip_bfloat162 r = __float22bfloat162_rn(t);
    unsigned u;
    __builtin_memcpy(&u, &r, 4);
    return u;
}
static __device__ __forceinline__ float elem(const float4& v, int j) {
    return reinterpret_cast<const float*>(&v)[j];
}

#define LGKM_BARRIER() do { \
    asm volatile("s_waitcnt lgkmcnt(0)" ::: "memory"); \
    __builtin_amdgcn_sched_barrier(0); \
    __builtin_amdgcn_s_barrier(); \
    __builtin_amdgcn_sched_barrier(0); } while (0)

// ---------------------------------------------------------------------------
// Kernel 1: shared-T bf16-MFMA syrk. 512 blocks x 256 thr (4 waves),
// 2 blocks/CU = 8 waves/CU. 9 tiles/wave (small acc -> AGPR, VGPR ~100).
// Double-buffered shared T; 2-set per-thread reg staging with compiler
// counted waits; RAW s_barrier + lgkmcnt(0) ONLY (in-flight global loads
// are never drained at barriers -- the R8 killer removed).
// ---------------------------------------------------------------------------
__global__ __launch_bounds__(256) void cov_kernel(const float* __restrict__ x,
                                                  float* __restrict__ ws)
{
    __shared__ __align__(16) char T2[2][FF * TSTRIDE];   // 2 x 9216 B
    __shared__ float csr[8][FF];                          // 4 KB scratch
    __shared__ float redsa[4];

    const int b = blockIdx.x >> 3;
    const int s = blockIdx.x & 7;
    const float* xb = x + ((size_t)b * TN + (size_t)s * 512) * FF;

    const int tid  = threadIdx.x;
    const int w    = tid >> 6;     // wave 0..3
    const int lane = tid & 63;
    const int m    = lane & 15;    // MFMA frag coords
    const int h    = lane >> 4;    // 0..3
    const int c    = tid & 31;     // staging f-quad
    const int rg   = tid >> 5;     // staging row-group 0..7 (rows rg*4..rg*4+3)

    f32x4 acc[9];
#pragma unroll
    for (int i = 0; i < 9; ++i) acc[i] = (f32x4){0.f, 0.f, 0.f, 0.f};
    float csum[4] = {0.f, 0.f, 0.f, 0.f};
    float sabs = 0.f;

    float4 A[4], B[4];             // two staging sets, static-indexed

    // tile kt: thread loads rows kt*32 + rg*4 + i (i<4), 16B f-quad c
    auto load = [&](int kt, float4* dst) {
        const float* a = xb + ((size_t)kt * KT + rg * 4) * FF + c * 4;
#pragma unroll
        for (int i = 0; i < 4; ++i)
            dst[i] = *(const float4*)(a + (size_t)i * FF);
    };

    // convert staged rows into T buffer (k positions rg*4..rg*4+3)
    auto convert = [&](const float4* sv, char* T) {
#pragma unroll
        for (int j = 0; j < 4; ++j) {
            const float v0 = elem(sv[0], j), v1 = elem(sv[1], j);
            const float v2 = elem(sv[2], j), v3 = elem(sv[3], j);
            csum[j] += (v0 + v1) + (v2 + v3);
            sabs += (fabsf(v0) + fabsf(v1)) + (fabsf(v2) + fabsf(v3));
            *(uint2*)(T + (c * 4 + j) * TSTRIDE + rg * 8) =
                (uint2){pk2(v0, v1), pk2(v2, v3)};
        }
    };

    auto frag = [&](const char* T, int ft) -> bf16x8_t {
        const char* p = T + (ft * 16 + m) * TSTRIDE + h * 16;
        short4_t lo = *(const short4_t*)p;
        short4_t hi = *(const short4_t*)(p + 8);
        return (bf16x8_t){lo.x,lo.y,lo.z,lo.w,hi.x,hi.y,hi.z,hi.w};
    };

    auto domfma = [&](const char* T) {
#pragma unroll
        for (int i = 0; i < 9; ++i) {
            bf16x8_t a = frag(T, TR[w][i]);     // addresses dynamic (OK);
            bf16x8_t bb = frag(T, TC[w][i]);    // acc index i static (rule #20)
            acc[i] = __builtin_amdgcn_mfma_f32_16x16x32_bf16(a, bb, acc[i], 0, 0, 0);
        }
    };

    // ---- prologue: A=tile0 converted; B=tile1 in flight ----
    load(0, A);
    convert(A, T2[0]);             // compiler waits on A only
    load(1, B);
    LGKM_BARRIER();

    // ---- main loop: one raw barrier per phase, NO vmcnt drains ----
#pragma unroll 1
    for (int p = 0; p < NKT; ++p) {
        if (p + 2 < NKT) load(p + 2, (p & 1) ? B : A);   // even p: A=even tile
        domfma(T2[p & 1]);
        if (p + 1 < NKT) {
            convert((p & 1) ? A : B, T2[(p + 1) & 1]);   // counted wait by dataflow
            LGKM_BARRIER();
        }
    }

    // ---- epilogue: per-wave tiles are disjoint -> direct stores ----
    float* Pb = ws + P_OFF + (size_t)blockIdx.x * PART_FLOATS;
#pragma unroll
    for (int i = 0; i < 9; ++i) {
        const int tn = TT[w][i];
#pragma unroll
        for (int q = 0; q < 4; ++q)
            Pb[tn * TILE_ELEMS + (h * 4 + q) * 16 + m] = acc[i][q];
    }

    // ---- column sums + sum|x| ----
    __syncthreads();
#pragma unroll
    for (int j = 0; j < 4; ++j) csr[rg][c * 4 + j] = csum[j];
#pragma unroll
    for (int off = 32; off > 0; off >>= 1) sabs += __shfl_down(sabs, off, 64);
    if (lane == 0) redsa[w] = sabs;
    __syncthreads();
    if (tid < FF) {
        float t = 0.f;
#pragma unroll
        for (int r = 0; r < 8; ++r) t += csr[r][tid];
        atomicAdd(&ws[SUM0_OFF + b * FF + tid], t);
    }
    if (tid == 0)
        atomicAdd(&ws[SABS_OFF], (redsa[0] + redsa[1]) + (redsa[2] + redsa[3]));
}

// ---------------------------------------------------------------------------
// Kernel 2: reduce 8 chunk-partials -> R, fused mean/rstd for diag tiles.
// ---------------------------------------------------------------------------
__global__ __launch_bounds__(256) void reduce_stats_kernel(float* __restrict__ ws)
{
    const int bb = blockIdx.x / NTILE_UP;
    const int t  = blockIdx.x % NTILE_UP;
    const int e  = t * 256 + threadIdx.x;
    const float* P = ws + P_OFF + (size_t)bb * SPLIT * PART_FLOATS + e;
    float a = 0.f;
#pragma unroll
    for (int s = 0; s < SPLIT; ++s) a += P[(size_t)s * PART_FLOATS];
    ws[R_OFF + (size_t)bb * PART_FLOATS + e] = a;

    const int tr = kDiagTr[t];
    if (tr >= 0) {
        const int i = threadIdx.x >> 4, j = threadIdx.x & 15;
        if (i == j) {
            const int idx = bb * FF + tr * 16 + i;
            const float mean = ws[SUM0_OFF + idx] * (1.f / TN);
            const float var  = a * (1.f / TN) - mean * mean;
            ws[MEAN_OFF + idx] = mean;
            ws[RSTD_OFF + idx] = rsqrtf(fmaxf(var, 1e-30f));
        }
    }
}

// ---------------------------------------------------------------------------
// Kernel 3: corr_avg_abs + strict upper-tri sum; last block writes outputs.
// ---------------------------------------------------------------------------
__global__ __launch_bounds__(256) void corr_final_kernel(float* __restrict__ ws,
                                                         float* __restrict__ out)
{
    __shared__ float red[4];
    const int p = blockIdx.x * 256 + threadIdx.x;
    const int f = p >> 7, g = p & 127;

    float v = 0.f;
    if (g > f) {
        const int tidx = kRowBaseRT[f >> 4] + ((g >> 4) - (f >> 4));
        const size_t off = (size_t)tidx * TILE_ELEMS + (f & 15) * 16 + (g & 15);
        float accum = 0.f;
#pragma unroll 8
        for (int b = 0; b < BB; ++b) {
            const float s2 = ws[R_OFF + (size_t)b * PART_FLOATS + off];
            const float mf = ws[MEAN_OFF + b * FF + f];
            const float mg = ws[MEAN_OFF + b * FF + g];
            const float rf = ws[RSTD_OFF + b * FF + f];
            const float rg = ws[RSTD_OFF + b * FF + g];
            accum += (s2 * (1.f / TN) - mf * mg) * rf * rg;
        }
        v = fabsf(accum * (1.f / BB));
    }

#pragma unroll
    for (int off = 32; off > 0; off >>= 1) v += __shfl_down(v, off, 64);
    const int lane = threadIdx.x & 63, wid = threadIdx.x >> 6;
    if (lane == 0) red[wid] = v;
    __syncthreads();
    if (threadIdx.x == 0) {
        atomicAdd(&ws[TRI_OFF], (red[0] + red[1]) + (red[2] + red[3]));
        __threadfence();
        const float old = atomicAdd(&ws[DONE_OFF], 1.0f);
        if (old == 63.0f) {
            const float tri  = atomicAdd(&ws[TRI_OFF], 0.0f);
            const float sabs = ws[SABS_OFF];
            out[0] = tri * (0.01f / 8128.f);
            out[1] = tri;
            out[2] = sabs * (1.f / FF);
        }
    }
}

extern "C" void kernel_launch(void* const* d_in, const int* in_sizes, int n_in,
                              void* d_out, int out_size, void* d_ws, size_t ws_size,
                              hipStream_t stream)
{
    const float* x = (const float*)d_in[0];
    float* out = (float*)d_out;
    float* ws = (float*)d_ws;

    (void)hipMemsetAsync(d_ws, 0, (size_t)ZERO_FLOATS * sizeof(float), stream);

    hipLaunchKernelGGL(cov_kernel,          dim3(NBLK), dim3(256), 0, stream, x, ws);
    hipLaunchKernelGGL(reduce_stats_kernel, dim3(BB * NTILE_UP), dim3(256), 0, stream, ws);
    hipLaunchKernelGGL(corr_final_kernel,   dim3((FF * FF) / 256), dim3(256), 0, stream, ws, out);
}